// Round 3
// baseline (244.960 us; speedup 1.0000x reference)
//
#include <hip/hip_runtime.h>

// Problem constants (from reference setup_inputs)
#define N_PRE_C   50000
#define N_TYPES_C 20
#define N_BASIS_C 5
#define NB        2                    // batches
#define WORDS     784                  // ceil(50000/64)=782, padded to 784
#define BCAP      1024                 // per-block LDS entry buffer (expected ~82/block)

typedef unsigned long long ull;

// ---------------------------------------------------------------------------
// Kernel 1: pack rec_z_buf (B x N_PRE floats, binary) into a bitmask.
// Layout: mask[word][b] interleaved so one 16B read covers both batches.
// Also zeroes out_t (grid-stride float4) and the global list counter.
// ---------------------------------------------------------------------------
__global__ __launch_bounds__(256) void pack_spikes(const float* __restrict__ rec_z,
                                                   ull* __restrict__ mask,
                                                   float4* __restrict__ zbuf,
                                                   int zquads,
                                                   int* __restrict__ cnt) {
    const int b = blockIdx.y;
    const int i = blockIdx.x * 256 + threadIdx.x;   // [0, WORDS*64)
    float v = 0.f;
    if (i < N_PRE_C) v = rec_z[b * N_PRE_C + i];
    const ull m = __ballot(v > 0.f);
    if ((threadIdx.x & 63) == 0) mask[(i >> 6) * NB + b] = m;
    if (cnt != nullptr && b == 0 && i == 0) *cnt = 0;

    if (zbuf != nullptr) {
        const int nt = gridDim.x * gridDim.y * 256;
        int q = (blockIdx.y * gridDim.x + blockIdx.x) * 256 + threadIdx.x;
        const float4 z = make_float4(0.f, 0.f, 0.f, 0.f);
        for (; q < zquads; q += nt) zbuf[q] = z;
    }
}

// ---------------------------------------------------------------------------
// Phase A: pure-stream compaction. Reads ONLY idx (80 MB; w/sid untouched
// here -> stream halves). For each firing (synapse,batch) pair, pushes
// {dst_row*20, syn_id} into an LDS buffer; block flushes with ONE returning
// global atomic + coalesced stores. No scattered VMEM in the stream path.
// One-shot threads (8 synapses each) -> no loop-head vmcnt hazard.
// Overflow paths (BCAP ~12 sigma, list cap) keep correctness non-probabilistic.
// ---------------------------------------------------------------------------
__device__ __forceinline__ void push_e(unsigned dst20, unsigned s,
                                       uint2* __restrict__ buf, int* __restrict__ bcnt,
                                       uint2* __restrict__ list, int* __restrict__ cnt,
                                       int cap,
                                       const float* __restrict__ w,
                                       const int* __restrict__ sid,
                                       float* __restrict__ out_t) {
    const int slot = atomicAdd(bcnt, 1);             // LDS atomic
    if (slot < BCAP) { buf[slot] = make_uint2(dst20, s); return; }
    const int g = atomicAdd(cnt, 1);                 // cold: LDS buffer full
    if (g < cap) { list[g] = make_uint2(dst20, s); return; }
    unsafeAtomicAdd(out_t + dst20 + sid[s], w[s]);   // last resort (tiny ws)
}

__global__ __launch_bounds__(256) void syn_compact(
    const int4* __restrict__ idx4,     // 2 synapses per int4 (post,pre,post,pre)
    const ull*  __restrict__ mask,
    uint2* __restrict__ list, int* __restrict__ cnt, int cap,
    const float* __restrict__ w, const int* __restrict__ sid,
    float* __restrict__ out_t,
    int n_post, int n_syn) {
    __shared__ __align__(16) ull sm[WORDS][2];
    __shared__ __align__(16) uint2 buf[BCAP];
    __shared__ int bcnt, gbase;
    {   // stage mask with 16B loads
        const ulonglong2* msrc = (const ulonglong2*)mask;
        ulonglong2* mdst = (ulonglong2*)sm;
        for (int t = threadIdx.x; t < WORDS; t += 256) mdst[t] = msrc[t];
    }
    if (threadIdx.x == 0) bcnt = 0;
    __syncthreads();
    const ulonglong2* sm2 = (const ulonglong2*)sm;
    const unsigned np20 = (unsigned)n_post * N_TYPES_C;

    auto proc = [&](int post, int pre, unsigned s) {
        const ulonglong2 mw = sm2[pre >> 6];
        const ull bit = 1ull << (pre & 63);
        if (((mw.x | mw.y) & bit) == 0ull) return;   // ~96% early-out
        const unsigned d20 = (unsigned)post * N_TYPES_C;
        if (mw.x & bit) push_e(d20, s, buf, &bcnt, list, cnt, cap, w, sid, out_t);
        if (mw.y & bit) push_e(d20 + np20, s, buf, &bcnt, list, cnt, cap, w, sid, out_t);
    };

    const int gt = blockIdx.x * 256 + threadIdx.x;
    const long s0 = (long)gt * 8;                    // 8 synapses per thread
    if (s0 < n_syn) {
        if (s0 + 8 <= n_syn) {
            // 4 x 16B coalesced loads = the entire per-thread stream
            const int4 a = idx4[gt * 4 + 0];
            const int4 b = idx4[gt * 4 + 1];
            const int4 c = idx4[gt * 4 + 2];
            const int4 d = idx4[gt * 4 + 3];
            const unsigned u = (unsigned)s0;
            proc(a.x, a.y, u + 0); proc(a.z, a.w, u + 1);
            proc(b.x, b.y, u + 2); proc(b.z, b.w, u + 3);
            proc(c.x, c.y, u + 4); proc(c.z, c.w, u + 5);
            proc(d.x, d.y, u + 6); proc(d.z, d.w, u + 7);
        } else {
            const int2* p = (const int2*)idx4;
            for (long s = s0; s < n_syn; ++s) {
                const int2 e = p[s];
                proc(e.x, e.y, (unsigned)s);
            }
        }
    }

    // block flush: one returning atomic, then coalesced 8B stores
    __syncthreads();
    const int n = bcnt < BCAP ? bcnt : BCAP;
    if (threadIdx.x == 0) gbase = atomicAdd(cnt, n);
    __syncthreads();
    for (int i = threadIdx.x; i < n; i += 256) {
        const int g = gbase + i;
        const uint2 e = buf[i];
        if (g < cap) list[g] = e;
        else unsafeAtomicAdd(out_t + e.x + sid[e.y], w[e.y]);  // last resort
    }
}

// ---------------------------------------------------------------------------
// Phase B: pure scatter-apply. ~400K entries: coalesced list read, two 4B
// gathers (w, sid touched ONLY for firing synapses), one fire-and-forget
// atomic. Huge TLP; no stream to poison.
// ---------------------------------------------------------------------------
__global__ __launch_bounds__(256) void syn_apply(
    const float* __restrict__ w, const int* __restrict__ sid,
    const uint2* __restrict__ list, const int* __restrict__ cnt, int cap,
    float* __restrict__ out_t) {
    int n = *cnt;
    if (n > cap) n = cap;
    const int stride = gridDim.x * 256;
    for (int i = blockIdx.x * 256 + threadIdx.x; i < n; i += stride) {
        const uint2 e = list[i];
        unsafeAtomicAdd(out_t + e.x + (unsigned)sid[e.y], w[e.y]);
    }
}

// ---------------------------------------------------------------------------
// Kernel 3: combine out_t [rows][20] x basis [20][5] -> out [rows][5].
// ---------------------------------------------------------------------------
__global__ __launch_bounds__(256) void combine_basis(
    const float* __restrict__ out_t,
    const float* __restrict__ basis,   // [N_TYPES][N_BASIS]
    float* __restrict__ out, int rows) {
    __shared__ float sb[N_TYPES_C * N_BASIS_C];
    if (threadIdx.x < N_TYPES_C * N_BASIS_C) sb[threadIdx.x] = basis[threadIdx.x];
    __syncthreads();

    const int r = blockIdx.x * 256 + threadIdx.x;
    if (r >= rows) return;
    const float4* p = (const float4*)(out_t + (long)r * N_TYPES_C);
    float4 v0 = p[0], v1 = p[1], v2 = p[2], v3 = p[3], v4 = p[4];
    float vt[N_TYPES_C] = {v0.x, v0.y, v0.z, v0.w, v1.x, v1.y, v1.z, v1.w,
                           v2.x, v2.y, v2.z, v2.w, v3.x, v3.y, v3.z, v3.w,
                           v4.x, v4.y, v4.z, v4.w};
    float acc[N_BASIS_C] = {0.f, 0.f, 0.f, 0.f, 0.f};
    #pragma unroll
    for (int t = 0; t < N_TYPES_C; ++t) {
        #pragma unroll
        for (int k = 0; k < N_BASIS_C; ++k)
            acc[k] += vt[t] * sb[t * N_BASIS_C + k];   // sb read is a broadcast
    }
    float* o = out + (long)r * N_BASIS_C;
    #pragma unroll
    for (int k = 0; k < N_BASIS_C; ++k) o[k] = acc[k];
}

// ---------------------------------------------------------------------------
// Fallback (only if ws too small): direct 5-atomic scatter into out.
// ---------------------------------------------------------------------------
__device__ __forceinline__ void proc_direct(int post, int pre, float wv, int tt,
                                            const ull (*sm)[2],
                                            const float (*sb)[N_BASIS_C],
                                            float* __restrict__ out, int n_post) {
    const int word = pre >> 6;
    const ull m0 = sm[word][0], m1 = sm[word][1];
    const ull bit = 1ull << (pre & 63);
    if (((m0 | m1) & bit) == 0ull) return;
    const float* bs = sb[tt];
    float c[N_BASIS_C];
    #pragma unroll
    for (int k = 0; k < N_BASIS_C; ++k) c[k] = wv * bs[k];
    if (m0 & bit) {
        float* o = out + (long)post * N_BASIS_C;
        #pragma unroll
        for (int k = 0; k < N_BASIS_C; ++k) unsafeAtomicAdd(o + k, c[k]);
    }
    if (m1 & bit) {
        float* o = out + (long)(n_post + post) * N_BASIS_C;
        #pragma unroll
        for (int k = 0; k < N_BASIS_C; ++k) unsafeAtomicAdd(o + k, c[k]);
    }
}

__global__ __launch_bounds__(256) void syn_scatter_direct(
    const int4* __restrict__ idx2, const float4* __restrict__ w4,
    const int4* __restrict__ sid4, const float* __restrict__ basis,
    const ull* __restrict__ mask, float* __restrict__ out,
    int n_post, int n_syn) {
    __shared__ __align__(16) ull sm[WORDS][2];
    __shared__ float sb[N_TYPES_C][N_BASIS_C];
    for (int t = threadIdx.x; t < WORDS * 2; t += 256) ((ull*)sm)[t] = mask[t];
    for (int t = threadIdx.x; t < N_TYPES_C * N_BASIS_C; t += 256)
        ((float*)sb)[t] = basis[t];
    __syncthreads();
    const int t = blockIdx.x * 256 + threadIdx.x;
    const long base = (long)t * 4;
    if (base >= n_syn) return;
    if (base + 4 <= n_syn) {
        const int4   p01 = idx2[(long)t * 2];
        const int4   p23 = idx2[(long)t * 2 + 1];
        const float4 wv  = w4[t];
        const int4   sv  = sid4[t];
        proc_direct(p01.x, p01.y, wv.x, sv.x, sm, sb, out, n_post);
        proc_direct(p01.z, p01.w, wv.y, sv.y, sm, sb, out, n_post);
        proc_direct(p23.x, p23.y, wv.z, sv.z, sm, sb, out, n_post);
        proc_direct(p23.z, p23.w, wv.w, sv.w, sm, sb, out, n_post);
    } else {
        const int*   idx = (const int*)idx2;
        const float* w   = (const float*)w4;
        const int*   sid = (const int*)sid4;
        for (long s = base; s < n_syn; ++s)
            proc_direct(idx[2 * s], idx[2 * s + 1], w[s], sid[s], sm, sb, out, n_post);
    }
}

extern "C" void kernel_launch(void* const* d_in, const int* in_sizes, int n_in,
                              void* d_out, int out_size, void* d_ws, size_t ws_size,
                              hipStream_t stream) {
    const float* rec_z   = (const float*)d_in[0];
    const float* weights = (const float*)d_in[1];
    const float* basis   = (const float*)d_in[2];
    const int*   synidx  = (const int*)d_in[3];
    const int*   synids  = (const int*)d_in[4];
    float*       out     = (float*)d_out;

    const int n_syn  = in_sizes[4];
    const int rows   = out_size / N_BASIS_C;       // NB * n_post
    const int n_post = rows / NB;

    // Workspace layout: out_t [rows][20] | mask | cnt(16B) | list[...]
    const size_t out_t_bytes = (size_t)rows * N_TYPES_C * sizeof(float);
    const size_t mask_bytes  = (size_t)WORDS * NB * sizeof(ull);
    const size_t fixed_bytes = out_t_bytes + mask_bytes + 16;
    // expected list: ~n_syn * 2 * SPIKE_P * 8B ~= 3.2 MB; require 2x headroom
    const size_t want_list   = (size_t)(n_syn / 8 + 1024) * 8;

    if (ws_size >= fixed_bytes + want_list) {
        float* out_t = (float*)d_ws;
        ull*   mask  = (ull*)((char*)d_ws + out_t_bytes);
        int*   cnt   = (int*)((char*)d_ws + out_t_bytes + mask_bytes);
        uint2* list  = (uint2*)((char*)d_ws + fixed_bytes);
        const size_t cap_sz = (ws_size - fixed_bytes) / sizeof(uint2);
        const int cap = cap_sz > 0x7ffffff0ull ? 0x7ffffff0 : (int)cap_sz;

        const int zquads = (int)(out_t_bytes / sizeof(float4));
        pack_spikes<<<dim3(WORDS * 64 / 256, NB), 256, 0, stream>>>(
            rec_z, mask, (float4*)out_t, zquads, cnt);

        const int n_thr  = (n_syn + 7) / 8;
        const int blocks = (n_thr + 255) / 256;
        syn_compact<<<blocks, 256, 0, stream>>>(
            (const int4*)synidx, mask, list, cnt, cap,
            weights, synids, out_t, n_post, n_syn);

        syn_apply<<<2048, 256, 0, stream>>>(weights, synids, list, cnt, cap, out_t);

        combine_basis<<<(rows + 255) / 256, 256, 0, stream>>>(out_t, basis, out, rows);
    } else {
        // Fallback: direct 5-atomic scatter.
        ull* mask = (ull*)d_ws;
        hipMemsetAsync(d_out, 0, (size_t)out_size * sizeof(float), stream);
        pack_spikes<<<dim3(WORDS * 64 / 256, NB), 256, 0, stream>>>(
            rec_z, mask, nullptr, 0, nullptr);
        const int blocks = ((n_syn + 3) / 4 + 255) / 256;
        syn_scatter_direct<<<blocks, 256, 0, stream>>>(
            (const int4*)synidx, (const float4*)weights, (const int4*)synids,
            basis, mask, out, n_post, n_syn);
    }
}

// Round 4
// 198.686 us; speedup vs baseline: 1.2329x; 1.2329x over previous
//
#include <hip/hip_runtime.h>

// Problem constants (from reference setup_inputs)
#define N_PRE_C   50000
#define N_TYPES_C 20
#define N_BASIS_C 5
#define NB        2                    // batches
#define WORDS32   1568                 // ceil(50000/32)=1563, padded to 1568 (wave-aligned)

typedef unsigned long long ull;
typedef unsigned int uint_t;

// ---------------------------------------------------------------------------
// Kernel 1: pack rec_z_buf (B x N_PRE floats, binary) into a 32-bit bitmask.
// Layout: mask32[word32][b] (uint per batch) so one 8B read covers both
// batches -> scatter's random lookup is ds_read_b64, not b128.
// Also zeroes out_t (grid-stride float4): no separate memset dispatch.
// ---------------------------------------------------------------------------
__global__ __launch_bounds__(256) void pack_spikes(const float* __restrict__ rec_z,
                                                   uint_t* __restrict__ mask32,
                                                   float4* __restrict__ zbuf,
                                                   int zquads) {
    const int b = blockIdx.y;
    const int i = blockIdx.x * 256 + threadIdx.x;   // [0, WORDS32*32)
    float v = 0.f;
    if (i < N_PRE_C) v = rec_z[b * N_PRE_C + i];
    const ull m = __ballot(v > 0.f);
    if ((threadIdx.x & 63) == 0) {                  // i is a multiple of 64
        const int w32 = i >> 5;                     // even
        mask32[(w32 + 0) * NB + b] = (uint_t)(m & 0xffffffffull);
        mask32[(w32 + 1) * NB + b] = (uint_t)(m >> 32);
    }

    if (zbuf != nullptr) {
        const int nt = gridDim.x * gridDim.y * 256;
        int q = (blockIdx.y * gridDim.x + blockIdx.x) * 256 + threadIdx.x;
        const float4 z = make_float4(0.f, 0.f, 0.f, 0.f);
        for (; q < zquads; q += nt) zbuf[q] = z;
    }
}

// ---------------------------------------------------------------------------
// Kernel 2: one-shot scatter (R0 skeleton - best measured) with:
//   (1) 8B ds_read_b64 mask lookups (uint2 = both batches) - half the LDS
//       gather traffic/conflict surface of the old 16B b128 lookups.
//   (2) w4/sid4 loaded ONLY when the quad has a firing synapse (~15% of
//       threads): stream drops 160 MB -> ~92 MB. Loads sit in a divergent
//       branch on a raw pointer -> compiler cannot speculate them.
// unsafeAtomicAdd = HW global_atomic_add_f32, no return (fire-and-forget).
// ---------------------------------------------------------------------------
__global__ __launch_bounds__(256) void syn_scatter_t(
    const int4*  __restrict__ idx2,    // 2 synapses per int4 (post,pre,post,pre)
    const float4* __restrict__ w4,
    const int4*  __restrict__ sid4,
    const uint2* __restrict__ mask2,   // [WORDS32] {b0,b1}
    float* __restrict__ out_t,         // [NB*n_post][N_TYPES] accumulator (zeroed)
    int n_post, int n_syn) {
    __shared__ __align__(16) uint2 sm[WORDS32];
    {   // stage mask with 16B loads (1568*8B = 12544B)
        const uint4* msrc = (const uint4*)mask2;
        uint4* mdst = (uint4*)sm;
        for (int t = threadIdx.x; t < WORDS32 / 2; t += 256) mdst[t] = msrc[t];
    }
    __syncthreads();

    const int t = blockIdx.x * 256 + threadIdx.x;
    const long base = (long)t * 4;
    if (base >= n_syn) return;
    const int np20 = n_post * N_TYPES_C;

    if (base + 4 <= n_syn) {
        // 32B of idx per thread, coalesced.
        const int4 p01 = idx2[t * 2];
        const int4 p23 = idx2[t * 2 + 1];
        // 4 random 8B LDS gathers (addresses straight from the idx loads).
        const uint2 m0 = sm[p01.y >> 5];
        const uint2 m1 = sm[p01.w >> 5];
        const uint2 m2 = sm[p23.y >> 5];
        const uint2 m3 = sm[p23.w >> 5];
        const uint_t b0 = 1u << (p01.y & 31);
        const uint_t b1 = 1u << (p01.w & 31);
        const uint_t b2 = 1u << (p23.y & 31);
        const uint_t b3 = 1u << (p23.w & 31);
        const uint_t f0 = (m0.x | m0.y) & b0;
        const uint_t f1 = (m1.x | m1.y) & b1;
        const uint_t f2 = (m2.x | m2.y) & b2;
        const uint_t f3 = (m3.x | m3.y) & b3;
        if (f0 | f1 | f2 | f3) {                    // ~15% of threads
            const float4 wv = w4[t];                // predicated 16B loads
            const int4   sv = sid4[t];
            if (f0) {
                const int o = p01.x * N_TYPES_C + sv.x;
                if (m0.x & b0) unsafeAtomicAdd(out_t + o, wv.x);
                if (m0.y & b0) unsafeAtomicAdd(out_t + o + np20, wv.x);
            }
            if (f1) {
                const int o = p01.z * N_TYPES_C + sv.y;
                if (m1.x & b1) unsafeAtomicAdd(out_t + o, wv.y);
                if (m1.y & b1) unsafeAtomicAdd(out_t + o + np20, wv.y);
            }
            if (f2) {
                const int o = p23.x * N_TYPES_C + sv.z;
                if (m2.x & b2) unsafeAtomicAdd(out_t + o, wv.z);
                if (m2.y & b2) unsafeAtomicAdd(out_t + o + np20, wv.z);
            }
            if (f3) {
                const int o = p23.z * N_TYPES_C + sv.w;
                if (m3.x & b3) unsafeAtomicAdd(out_t + o, wv.w);
                if (m3.y & b3) unsafeAtomicAdd(out_t + o + np20, wv.w);
            }
        }
    } else {
        const int*   idx = (const int*)idx2;
        const float* w   = (const float*)w4;
        const int*   sid = (const int*)sid4;
        for (long s = base; s < n_syn; ++s) {
            const int post = idx[2 * s], pre = idx[2 * s + 1];
            const uint2 mw = sm[pre >> 5];
            const uint_t bit = 1u << (pre & 31);
            if (((mw.x | mw.y) & bit) == 0u) continue;
            const int o = post * N_TYPES_C + sid[s];
            if (mw.x & bit) unsafeAtomicAdd(out_t + o, w[s]);
            if (mw.y & bit) unsafeAtomicAdd(out_t + o + np20, w[s]);
        }
    }
}

// ---------------------------------------------------------------------------
// Kernel 3: combine out_t [rows][20] x basis [20][5] -> out [rows][5].
// ---------------------------------------------------------------------------
__global__ __launch_bounds__(256) void combine_basis(
    const float* __restrict__ out_t,
    const float* __restrict__ basis,   // [N_TYPES][N_BASIS]
    float* __restrict__ out, int rows) {
    __shared__ float sb[N_TYPES_C * N_BASIS_C];
    if (threadIdx.x < N_TYPES_C * N_BASIS_C) sb[threadIdx.x] = basis[threadIdx.x];
    __syncthreads();

    const int r = blockIdx.x * 256 + threadIdx.x;
    if (r >= rows) return;
    const float4* p = (const float4*)(out_t + (long)r * N_TYPES_C);
    float4 v0 = p[0], v1 = p[1], v2 = p[2], v3 = p[3], v4 = p[4];
    float vt[N_TYPES_C] = {v0.x, v0.y, v0.z, v0.w, v1.x, v1.y, v1.z, v1.w,
                           v2.x, v2.y, v2.z, v2.w, v3.x, v3.y, v3.z, v3.w,
                           v4.x, v4.y, v4.z, v4.w};
    float acc[N_BASIS_C] = {0.f, 0.f, 0.f, 0.f, 0.f};
    #pragma unroll
    for (int t = 0; t < N_TYPES_C; ++t) {
        #pragma unroll
        for (int k = 0; k < N_BASIS_C; ++k)
            acc[k] += vt[t] * sb[t * N_BASIS_C + k];   // sb read is a broadcast
    }
    float* o = out + (long)r * N_BASIS_C;
    #pragma unroll
    for (int k = 0; k < N_BASIS_C; ++k) o[k] = acc[k];
}

// ---------------------------------------------------------------------------
// Fallback (only if ws too small): direct 5-atomic scatter into out.
// ---------------------------------------------------------------------------
__global__ __launch_bounds__(256) void syn_scatter_direct(
    const int4* __restrict__ idx2, const float4* __restrict__ w4,
    const int4* __restrict__ sid4, const float* __restrict__ basis,
    const uint2* __restrict__ mask2, float* __restrict__ out,
    int n_post, int n_syn) {
    __shared__ __align__(16) uint2 sm[WORDS32];
    __shared__ float sb[N_TYPES_C][N_BASIS_C];
    for (int t = threadIdx.x; t < WORDS32; t += 256) sm[t] = mask2[t];
    for (int t = threadIdx.x; t < N_TYPES_C * N_BASIS_C; t += 256)
        ((float*)sb)[t] = basis[t];
    __syncthreads();
    const int t = blockIdx.x * 256 + threadIdx.x;
    const long base = (long)t * 4;
    if (base >= n_syn) return;

    auto apply = [&](int post, int pre, float wv, int tt) {
        const uint2 mw = sm[pre >> 5];
        const uint_t bit = 1u << (pre & 31);
        if (((mw.x | mw.y) & bit) == 0u) return;
        const float* bs = sb[tt];
        float c[N_BASIS_C];
        #pragma unroll
        for (int k = 0; k < N_BASIS_C; ++k) c[k] = wv * bs[k];
        if (mw.x & bit) {
            float* o = out + (long)post * N_BASIS_C;
            #pragma unroll
            for (int k = 0; k < N_BASIS_C; ++k) unsafeAtomicAdd(o + k, c[k]);
        }
        if (mw.y & bit) {
            float* o = out + (long)(n_post + post) * N_BASIS_C;
            #pragma unroll
            for (int k = 0; k < N_BASIS_C; ++k) unsafeAtomicAdd(o + k, c[k]);
        }
    };

    if (base + 4 <= n_syn) {
        const int4   p01 = idx2[t * 2];
        const int4   p23 = idx2[t * 2 + 1];
        const float4 wv  = w4[t];
        const int4   sv  = sid4[t];
        apply(p01.x, p01.y, wv.x, sv.x);
        apply(p01.z, p01.w, wv.y, sv.y);
        apply(p23.x, p23.y, wv.z, sv.z);
        apply(p23.z, p23.w, wv.w, sv.w);
    } else {
        const int*   idx = (const int*)idx2;
        const float* w   = (const float*)w4;
        const int*   sid = (const int*)sid4;
        for (long s = base; s < n_syn; ++s)
            apply(idx[2 * s], idx[2 * s + 1], w[s], sid[s]);
    }
}

extern "C" void kernel_launch(void* const* d_in, const int* in_sizes, int n_in,
                              void* d_out, int out_size, void* d_ws, size_t ws_size,
                              hipStream_t stream) {
    const float* rec_z   = (const float*)d_in[0];
    const float* weights = (const float*)d_in[1];
    const float* basis   = (const float*)d_in[2];
    const int*   synidx  = (const int*)d_in[3];
    const int*   synids  = (const int*)d_in[4];
    float*       out     = (float*)d_out;

    const int n_syn  = in_sizes[4];
    const int rows   = out_size / N_BASIS_C;       // NB * n_post
    const int n_post = rows / NB;
    const int n_thr  = (n_syn + 3) / 4;
    const int blocks = (n_thr + 255) / 256;        // one-shot mapping

    // Workspace layout: out_t [rows][N_TYPES] floats, then mask32.
    const size_t out_t_bytes = (size_t)rows * N_TYPES_C * sizeof(float);  // mult of 16
    const size_t mask_bytes  = (size_t)WORDS32 * NB * sizeof(uint_t);

    if (ws_size >= out_t_bytes + mask_bytes) {
        float*  out_t  = (float*)d_ws;
        uint_t* mask32 = (uint_t*)((char*)d_ws + out_t_bytes);

        const int zquads = (int)(out_t_bytes / sizeof(float4));
        pack_spikes<<<dim3(WORDS32 * 32 / 256, NB), 256, 0, stream>>>(
            rec_z, mask32, (float4*)out_t, zquads);

        syn_scatter_t<<<blocks, 256, 0, stream>>>(
            (const int4*)synidx, (const float4*)weights, (const int4*)synids,
            (const uint2*)mask32, out_t, n_post, n_syn);

        combine_basis<<<(rows + 255) / 256, 256, 0, stream>>>(out_t, basis, out, rows);
    } else {
        // Fallback: direct 5-atomic scatter.
        uint_t* mask32 = (uint_t*)d_ws;
        hipMemsetAsync(d_out, 0, (size_t)out_size * sizeof(float), stream);
        pack_spikes<<<dim3(WORDS32 * 32 / 256, NB), 256, 0, stream>>>(
            rec_z, mask32, nullptr, 0);
        syn_scatter_direct<<<blocks, 256, 0, stream>>>(
            (const int4*)synidx, (const float4*)weights, (const int4*)synids,
            basis, (const uint2*)mask32, out, n_post, n_syn);
    }
}